// Round 1
// baseline (252.237 us; speedup 1.0000x reference)
//
#include <hip/hip_runtime.h>

// Problem constants (B, H, N, D, W) = (2, 12, 2048, 128, 64)
constexpr int Bc = 2;
constexpr int Hc = 12;
constexpr int Nc = 2048;   // power of two -> bid & (Nc-1)
constexpr int Dc = 128;
constexpr int Wc = 64;
constexpr float SCALE = 0.08838834764831845f;  // 1/sqrt(128)

// One block (256 threads) handles one query row (b, h, n).
//  Phase 1: scores  -- 4 threads per column, coalesced 64B k-row chunks
//  Phase 2: softmax -- wave 0 butterfly over W=64
//  Phase 3: PV      -- 8 groups x 32 threads, fully coalesced 512B v-rows
__global__ __launch_bounds__(256) void sca_kernel(
    const float* __restrict__ q,
    const float* __restrict__ k,
    const float* __restrict__ v,
    const int*   __restrict__ col_ids,
    float*       __restrict__ out)
{
    const int bid = blockIdx.x;           // (b*H + h)*N + n
    const int n   = bid & (Nc - 1);
    const int bh  = bid >> 11;            // / Nc
    const int t   = threadIdx.x;

    __shared__ int   s_cols[Wc];
    __shared__ float s_scores[Wc];
    __shared__ float s_probs[Wc];
    __shared__ float s_red[8 * Dc];       // 8 partial out-vectors, 4 KiB

    if (t < Wc) s_cols[t] = col_ids[n * Wc + t];

    const float* qrow  = q + ((size_t)bh * Nc + n) * Dc;
    const float* kbase = k + (size_t)bh * Nc * Dc;
    const float* vbase = v + (size_t)bh * Nc * Dc;

    __syncthreads();

    // ---------- Phase 1: scores ----------
    {
        const int w = t >> 2;             // column 0..63
        const int p = t & 3;              // quarter of the D dimension
        const int c = s_cols[w];
        const float4* krow = (const float4*)(kbase + (size_t)c * Dc);
        const float4* q4   = (const float4*)qrow;
        float acc = 0.0f;
#pragma unroll
        for (int i = 0; i < 8; ++i) {
            const float4 kk = krow[p + 4 * i];   // 4 threads cover 64B contiguous
            const float4 qq = q4[p + 4 * i];     // broadcast via L1
            acc += kk.x * qq.x + kk.y * qq.y + kk.z * qq.z + kk.w * qq.w;
        }
        // reduce the 4 partials (threads 4w..4w+3 are adjacent lanes)
        acc += __shfl_xor(acc, 1);
        acc += __shfl_xor(acc, 2);
        if (p == 0) s_scores[w] = acc * SCALE;
    }
    __syncthreads();

    // ---------- Phase 2: softmax over W=64 (wave 0) ----------
    if (t < 64) {
        const float s = s_scores[t];
        float m = s;
#pragma unroll
        for (int off = 32; off > 0; off >>= 1) m = fmaxf(m, __shfl_xor(m, off));
        const float e = __expf(s - m);
        float l = e;
#pragma unroll
        for (int off = 32; off > 0; off >>= 1) l += __shfl_xor(l, off);
        s_probs[t] = e / l;
    }
    __syncthreads();

    // ---------- Phase 3: PV ----------
    {
        const int j = t & 31;             // float4 index within D (32 * 4 = 128)
        const int g = t >> 5;             // group 0..7
        float4 acc = make_float4(0.f, 0.f, 0.f, 0.f);
#pragma unroll
        for (int i = 0; i < 8; ++i) {
            const int w  = g * 8 + i;
            const float pr = s_probs[w];
            const int   c  = s_cols[w];
            const float4 vv = ((const float4*)(vbase + (size_t)c * Dc))[j];
            acc.x += pr * vv.x;
            acc.y += pr * vv.y;
            acc.z += pr * vv.z;
            acc.w += pr * vv.w;
        }
        float4* red4 = (float4*)s_red;
        red4[g * 32 + j] = acc;           // [g][j] as float4
    }
    __syncthreads();

    // reduce 8 partials and store
    if (t < Dc) {
        float s = 0.0f;
#pragma unroll
        for (int g = 0; g < 8; ++g) s += s_red[g * Dc + t];
        out[((size_t)bh * Nc + n) * Dc + t] = s;
    }
}

extern "C" void kernel_launch(void* const* d_in, const int* in_sizes, int n_in,
                              void* d_out, int out_size, void* d_ws, size_t ws_size,
                              hipStream_t stream) {
    const float* q       = (const float*)d_in[0];
    const float* k       = (const float*)d_in[1];
    const float* v       = (const float*)d_in[2];
    const int*   col_ids = (const int*)  d_in[3];
    float*       out     = (float*)d_out;

    const int n_rows = Bc * Hc * Nc;      // 49152 blocks
    sca_kernel<<<dim3(n_rows), dim3(256), 0, stream>>>(q, k, v, col_ids, out);
}

// Round 2
// 234.117 us; speedup vs baseline: 1.0774x; 1.0774x over previous
//
#include <hip/hip_runtime.h>
#include <hip/hip_bf16.h>

// Problem constants (B, H, N, D, W) = (2, 12, 2048, 128, 64)
constexpr int Bc = 2;
constexpr int Hc = 12;
constexpr int Nc = 2048;   // power of two -> bid & (Nc-1)
constexpr int Dc = 128;
constexpr int Wc = 64;
constexpr float SCALE = 0.08838834764831845f;  // 1/sqrt(128)
constexpr int ELEMS = Bc * Hc * Nc * Dc;       // 6,291,456 per tensor

__device__ __forceinline__ float bf_lo(unsigned u) {
    u <<= 16;
    return __builtin_bit_cast(float, u);
}
__device__ __forceinline__ float bf_hi(unsigned u) {
    u &= 0xffff0000u;
    return __builtin_bit_cast(float, u);
}
__device__ __forceinline__ unsigned short f2bf(float f) {
    __hip_bfloat16 h = __float2bfloat16(f);   // RNE
    return __builtin_bit_cast(unsigned short, h);
}

// ---------- fp32 -> bf16 staging for k and v ----------
__global__ __launch_bounds__(256) void cvt_kernel(
    const float* __restrict__ k,
    const float* __restrict__ v,
    unsigned short* __restrict__ kb,
    unsigned short* __restrict__ vb)
{
    const int i = blockIdx.x * 256 + threadIdx.x;   // float4 index
    const float4 kk = ((const float4*)k)[i];
    const float4 vv = ((const float4*)v)[i];
    ushort4 ko, vo;
    ko.x = f2bf(kk.x); ko.y = f2bf(kk.y); ko.z = f2bf(kk.z); ko.w = f2bf(kk.w);
    vo.x = f2bf(vv.x); vo.y = f2bf(vv.y); vo.z = f2bf(vv.z); vo.w = f2bf(vv.w);
    ((ushort4*)kb)[i] = ko;
    ((ushort4*)vb)[i] = vo;
}

// ---------- main gather-attention kernel (bf16 k/v) ----------
// One block (256 threads) = one query row (b,h,n).
//  Phase 1: 4 threads/column, 4 x 16B bf16 k-chunks each, fp32 q, fp32 math
//  Phase 2: softmax over W=64 in wave 0
//  Phase 3: 8 groups x 32 threads; 8B (4 bf16) per thread -> 256B coalesced v-row
__global__ __launch_bounds__(256) void sca_bf16_kernel(
    const float* __restrict__ q,
    const unsigned short* __restrict__ kb,
    const unsigned short* __restrict__ vb,
    const int*   __restrict__ col_ids,
    float*       __restrict__ out)
{
    const int bid = blockIdx.x;
    const int n   = bid & (Nc - 1);
    const int bh  = bid >> 11;
    const int t   = threadIdx.x;

    __shared__ int   s_cols[Wc];
    __shared__ float s_scores[Wc];
    __shared__ float s_probs[Wc];
    __shared__ float s_red[8 * Dc];

    if (t < Wc) s_cols[t] = col_ids[n * Wc + t];

    const float*          qrow  = q  + ((size_t)bh * Nc + n) * Dc;
    const unsigned short* kbase = kb + (size_t)bh * Nc * Dc;
    const unsigned short* vbase = vb + (size_t)bh * Nc * Dc;

    __syncthreads();

    // ---------- Phase 1: scores ----------
    {
        const int w = t >> 2;             // column 0..63
        const int p = t & 3;              // quarter of D
        const int c = s_cols[w];
        const uint4*  krow = (const uint4*)(kbase + (size_t)c * Dc);  // 16 x 16B
        const float4* q4   = (const float4*)qrow;
        float acc = 0.0f;
#pragma unroll
        for (int i = 0; i < 4; ++i) {
            const uint4  kk = krow[p + 4 * i];          // 8 bf16, dims d0..d0+7
            const float4 qa = q4[(p + 4 * i) * 2];
            const float4 qb = q4[(p + 4 * i) * 2 + 1];
            acc += bf_lo(kk.x) * qa.x + bf_hi(kk.x) * qa.y
                 + bf_lo(kk.y) * qa.z + bf_hi(kk.y) * qa.w
                 + bf_lo(kk.z) * qb.x + bf_hi(kk.z) * qb.y
                 + bf_lo(kk.w) * qb.z + bf_hi(kk.w) * qb.w;
        }
        acc += __shfl_xor(acc, 1);
        acc += __shfl_xor(acc, 2);
        if (p == 0) s_scores[w] = acc * SCALE;
    }
    __syncthreads();

    // ---------- Phase 2: softmax (wave 0) ----------
    if (t < 64) {
        const float s = s_scores[t];
        float m = s;
#pragma unroll
        for (int off = 32; off > 0; off >>= 1) m = fmaxf(m, __shfl_xor(m, off));
        const float e = __expf(s - m);
        float l = e;
#pragma unroll
        for (int off = 32; off > 0; off >>= 1) l += __shfl_xor(l, off);
        s_probs[t] = e / l;
    }
    __syncthreads();

    // ---------- Phase 3: PV ----------
    {
        const int j = t & 31;             // 8B chunk within 256B row
        const int g = t >> 5;             // group 0..7
        float4 acc = make_float4(0.f, 0.f, 0.f, 0.f);
#pragma unroll
        for (int i = 0; i < 8; ++i) {
            const int   w  = g * 8 + i;
            const float pr = s_probs[w];
            const int   c  = s_cols[w];
            const uint2 vv = ((const uint2*)(vbase + (size_t)c * Dc))[j]; // 4 bf16
            acc.x += pr * bf_lo(vv.x);
            acc.y += pr * bf_hi(vv.x);
            acc.z += pr * bf_lo(vv.y);
            acc.w += pr * bf_hi(vv.y);
        }
        ((float4*)s_red)[g * 32 + j] = acc;
    }
    __syncthreads();

    if (t < Dc) {
        float s = 0.0f;
#pragma unroll
        for (int g = 0; g < 8; ++g) s += s_red[g * Dc + t];
        out[((size_t)bh * Nc + n) * Dc + t] = s;
    }
}

// ---------- fallback: original fp32 kernel (used only if ws too small) ----------
__global__ __launch_bounds__(256) void sca_kernel(
    const float* __restrict__ q,
    const float* __restrict__ k,
    const float* __restrict__ v,
    const int*   __restrict__ col_ids,
    float*       __restrict__ out)
{
    const int bid = blockIdx.x;
    const int n   = bid & (Nc - 1);
    const int bh  = bid >> 11;
    const int t   = threadIdx.x;

    __shared__ int   s_cols[Wc];
    __shared__ float s_scores[Wc];
    __shared__ float s_probs[Wc];
    __shared__ float s_red[8 * Dc];

    if (t < Wc) s_cols[t] = col_ids[n * Wc + t];

    const float* qrow  = q + ((size_t)bh * Nc + n) * Dc;
    const float* kbase = k + (size_t)bh * Nc * Dc;
    const float* vbase = v + (size_t)bh * Nc * Dc;

    __syncthreads();
    {
        const int w = t >> 2;
        const int p = t & 3;
        const int c = s_cols[w];
        const float4* krow = (const float4*)(kbase + (size_t)c * Dc);
        const float4* q4   = (const float4*)qrow;
        float acc = 0.0f;
#pragma unroll
        for (int i = 0; i < 8; ++i) {
            const float4 kk = krow[p + 4 * i];
            const float4 qq = q4[p + 4 * i];
            acc += kk.x * qq.x + kk.y * qq.y + kk.z * qq.z + kk.w * qq.w;
        }
        acc += __shfl_xor(acc, 1);
        acc += __shfl_xor(acc, 2);
        if (p == 0) s_scores[w] = acc * SCALE;
    }
    __syncthreads();
    if (t < 64) {
        const float s = s_scores[t];
        float m = s;
#pragma unroll
        for (int off = 32; off > 0; off >>= 1) m = fmaxf(m, __shfl_xor(m, off));
        const float e = __expf(s - m);
        float l = e;
#pragma unroll
        for (int off = 32; off > 0; off >>= 1) l += __shfl_xor(l, off);
        s_probs[t] = e / l;
    }
    __syncthreads();
    {
        const int j = t & 31;
        const int g = t >> 5;
        float4 acc = make_float4(0.f, 0.f, 0.f, 0.f);
#pragma unroll
        for (int i = 0; i < 8; ++i) {
            const int w  = g * 8 + i;
            const float pr = s_probs[w];
            const int   c  = s_cols[w];
            const float4 vv = ((const float4*)(vbase + (size_t)c * Dc))[j];
            acc.x += pr * vv.x;
            acc.y += pr * vv.y;
            acc.z += pr * vv.z;
            acc.w += pr * vv.w;
        }
        ((float4*)s_red)[g * 32 + j] = acc;
    }
    __syncthreads();
    if (t < Dc) {
        float s = 0.0f;
#pragma unroll
        for (int g = 0; g < 8; ++g) s += s_red[g * Dc + t];
        out[((size_t)bh * Nc + n) * Dc + t] = s;
    }
}

extern "C" void kernel_launch(void* const* d_in, const int* in_sizes, int n_in,
                              void* d_out, int out_size, void* d_ws, size_t ws_size,
                              hipStream_t stream) {
    const float* q       = (const float*)d_in[0];
    const float* k       = (const float*)d_in[1];
    const float* v       = (const float*)d_in[2];
    const int*   col_ids = (const int*)  d_in[3];
    float*       out     = (float*)d_out;

    const int n_rows = Bc * Hc * Nc;                 // 49152 blocks
    const size_t need = (size_t)2 * ELEMS * sizeof(unsigned short);  // 25.2 MB

    if (ws_size >= need) {
        unsigned short* kb = (unsigned short*)d_ws;
        unsigned short* vb = kb + ELEMS;
        cvt_kernel<<<dim3(ELEMS / 4 / 256), dim3(256), 0, stream>>>(k, v, kb, vb);
        sca_bf16_kernel<<<dim3(n_rows), dim3(256), 0, stream>>>(q, kb, vb, col_ids, out);
    } else {
        sca_kernel<<<dim3(n_rows), dim3(256), 0, stream>>>(q, k, v, col_ids, out);
    }
}

// Round 3
// 209.315 us; speedup vs baseline: 1.2051x; 1.1185x over previous
//
#include <hip/hip_runtime.h>
#include <hip/hip_bf16.h>

// Problem constants (B, H, N, D, W) = (2, 12, 2048, 128, 64)
constexpr int Bc = 2;
constexpr int Hc = 12;
constexpr int Nc = 2048;   // power of two
constexpr int Dc = 128;
constexpr int Wc = 64;
constexpr float SCALE = 0.08838834764831845f;  // 1/sqrt(128)
constexpr int ELEMS = Bc * Hc * Nc * Dc;       // 6,291,456 per tensor

__device__ __forceinline__ float bf_lo(unsigned u) {
    u <<= 16;
    return __builtin_bit_cast(float, u);
}
__device__ __forceinline__ float bf_hi(unsigned u) {
    u &= 0xffff0000u;
    return __builtin_bit_cast(float, u);
}
__device__ __forceinline__ unsigned short f2bf(float f) {
    __hip_bfloat16 h = __float2bfloat16(f);   // RNE
    return __builtin_bit_cast(unsigned short, h);
}

// ---------- fp32 -> bf16 staging for k and v ----------
__global__ __launch_bounds__(256) void cvt_kernel(
    const float* __restrict__ k,
    const float* __restrict__ v,
    unsigned short* __restrict__ kb,
    unsigned short* __restrict__ vb)
{
    const int i = blockIdx.x * 256 + threadIdx.x;   // float4 index
    const float4 kk = ((const float4*)k)[i];
    const float4 vv = ((const float4*)v)[i];
    ushort4 ko, vo;
    ko.x = f2bf(kk.x); ko.y = f2bf(kk.y); ko.z = f2bf(kk.z); ko.w = f2bf(kk.w);
    vo.x = f2bf(vv.x); vo.y = f2bf(vv.y); vo.z = f2bf(vv.z); vo.w = f2bf(vv.w);
    ((ushort4*)kb)[i] = ko;
    ((ushort4*)vb)[i] = vo;
}

// ---------- wave-per-row gather attention, zero block barriers ----------
// Wave (64 lanes) owns one query row. 4 waves per 256-block, fully independent.
//  QK:  4 column-passes; 4 lanes per column read 64B k-chunks (line-optimal);
//       q row cached in 32 VGPRs; quad shfl-reduce.
//  Softmax: quad-redundant butterfly over xor 4..32.
//  {col,prob} -> per-wave LDS (uint2); DS in-order per wave, no barrier.
//  PV:  2 groups x 32 lanes; one 256B v-row per group per iter (line-optimal);
//       cross-group shfl_xor(32); half-wave float4 store.
__global__ __launch_bounds__(256) void sca_wave_kernel(
    const float* __restrict__ q,
    const unsigned short* __restrict__ kb,
    const unsigned short* __restrict__ vb,
    const int*   __restrict__ col_ids,
    float*       __restrict__ out)
{
    const int t    = threadIdx.x;
    const int wv   = t >> 6;                 // wave 0..3
    const int lane = t & 63;
    const int row  = blockIdx.x * 4 + wv;    // bh*2048 + n
    const int n    = row & (Nc - 1);
    const int bh   = row >> 11;

    __shared__ uint2 s_pc[4][Wc];            // {col, prob} per wave, 2 KiB

    // each lane owns column `lane`
    const int c_own = col_ids[n * Wc + lane];

    const float*          qrow  = q  + (size_t)row * Dc;
    const unsigned short* kbase = kb + (size_t)bh * Nc * Dc;
    const unsigned short* vbase = vb + (size_t)bh * Nc * Dc;

    const int p  = lane & 3;                 // quarter within the quad
    const int qd = lane >> 2;                // quad index 0..15

    // q register cache: lane covers chunks p, p+4, p+8, p+12 (8 dims each)
    float4 qreg[8];
#pragma unroll
    for (int i = 0; i < 4; ++i) {
        qreg[2 * i]     = ((const float4*)qrow)[(p + 4 * i) * 2];
        qreg[2 * i + 1] = ((const float4*)qrow)[(p + 4 * i) * 2 + 1];
    }

    // ---------- QK: 4 passes of 16 columns ----------
    float sc[4];
    int   cs[4];
#pragma unroll
    for (int P = 0; P < 4; ++P) {
        const int w  = P * 16 + qd;
        const int cc = __shfl(c_own, w);
        cs[P] = cc;
        const uint4* krow = (const uint4*)(kbase + (size_t)cc * Dc);
        float acc = 0.0f;
#pragma unroll
        for (int i = 0; i < 4; ++i) {
            const uint4  kk = krow[p + 4 * i];
            const float4 qa = qreg[2 * i];
            const float4 qb = qreg[2 * i + 1];
            acc += bf_lo(kk.x) * qa.x + bf_hi(kk.x) * qa.y
                 + bf_lo(kk.y) * qa.z + bf_hi(kk.y) * qa.w
                 + bf_lo(kk.z) * qb.x + bf_hi(kk.z) * qb.y
                 + bf_lo(kk.w) * qb.z + bf_hi(kk.w) * qb.w;
        }
        acc += __shfl_xor(acc, 1);
        acc += __shfl_xor(acc, 2);
        sc[P] = acc * SCALE;
    }

    // ---------- softmax (quad-redundant over 16 quads) ----------
    float m = fmaxf(fmaxf(sc[0], sc[1]), fmaxf(sc[2], sc[3]));
#pragma unroll
    for (int off = 4; off < 64; off <<= 1) m = fmaxf(m, __shfl_xor(m, off));
    float e0 = __expf(sc[0] - m), e1 = __expf(sc[1] - m);
    float e2 = __expf(sc[2] - m), e3 = __expf(sc[3] - m);
    float s = e0 + e1 + e2 + e3;
#pragma unroll
    for (int off = 4; off < 64; off <<= 1) s += __shfl_xor(s, off);
    const float inv = 1.0f / s;

    // quad leaders publish {col, prob} for their 4 columns
    if (p == 0) {
        s_pc[wv][qd]      = make_uint2((unsigned)cs[0], __float_as_uint(e0 * inv));
        s_pc[wv][16 + qd] = make_uint2((unsigned)cs[1], __float_as_uint(e1 * inv));
        s_pc[wv][32 + qd] = make_uint2((unsigned)cs[2], __float_as_uint(e2 * inv));
        s_pc[wv][48 + qd] = make_uint2((unsigned)cs[3], __float_as_uint(e3 * inv));
    }
    __builtin_amdgcn_wave_barrier();   // ordering only; DS is in-order per wave

    // ---------- PV: 2 groups x 32 lanes ----------
    const int g = lane >> 5;                 // 0..1
    const int j = lane & 31;                 // 8B chunk within 256B v-row
    float4 acc = make_float4(0.f, 0.f, 0.f, 0.f);
#pragma unroll
    for (int i = 0; i < 32; ++i) {
        const uint2 pc = s_pc[wv][g * 32 + i];      // broadcast (2 addrs/wave)
        const float pr = __uint_as_float(pc.y);
        const uint2 vv = ((const uint2*)(vbase + (size_t)pc.x * Dc))[j];
        acc.x += pr * bf_lo(vv.x);
        acc.y += pr * bf_hi(vv.x);
        acc.z += pr * bf_lo(vv.y);
        acc.w += pr * bf_hi(vv.y);
    }
    // combine the two groups (same j, dims 4j..4j+3)
    acc.x += __shfl_xor(acc.x, 32);
    acc.y += __shfl_xor(acc.y, 32);
    acc.z += __shfl_xor(acc.z, 32);
    acc.w += __shfl_xor(acc.w, 32);

    if (lane < 32) ((float4*)(out + (size_t)row * Dc))[j] = acc;
}

// ---------- fallback: fp32 kernel (used only if ws too small) ----------
__global__ __launch_bounds__(256) void sca_kernel(
    const float* __restrict__ q,
    const float* __restrict__ k,
    const float* __restrict__ v,
    const int*   __restrict__ col_ids,
    float*       __restrict__ out)
{
    const int bid = blockIdx.x;
    const int n   = bid & (Nc - 1);
    const int bh  = bid >> 11;
    const int t   = threadIdx.x;

    __shared__ int   s_cols[Wc];
    __shared__ float s_scores[Wc];
    __shared__ float s_probs[Wc];
    __shared__ float s_red[8 * Dc];

    if (t < Wc) s_cols[t] = col_ids[n * Wc + t];

    const float* qrow  = q + ((size_t)bh * Nc + n) * Dc;
    const float* kbase = k + (size_t)bh * Nc * Dc;
    const float* vbase = v + (size_t)bh * Nc * Dc;

    __syncthreads();
    {
        const int w = t >> 2;
        const int p = t & 3;
        const int c = s_cols[w];
        const float4* krow = (const float4*)(kbase + (size_t)c * Dc);
        const float4* q4   = (const float4*)qrow;
        float acc = 0.0f;
#pragma unroll
        for (int i = 0; i < 8; ++i) {
            const float4 kk = krow[p + 4 * i];
            const float4 qq = q4[p + 4 * i];
            acc += kk.x * qq.x + kk.y * qq.y + kk.z * qq.z + kk.w * qq.w;
        }
        acc += __shfl_xor(acc, 1);
        acc += __shfl_xor(acc, 2);
        if (p == 0) s_scores[w] = acc * SCALE;
    }
    __syncthreads();
    if (t < 64) {
        const float sv = s_scores[t];
        float m = sv;
#pragma unroll
        for (int off = 32; off > 0; off >>= 1) m = fmaxf(m, __shfl_xor(m, off));
        const float e = __expf(sv - m);
        float l = e;
#pragma unroll
        for (int off = 32; off > 0; off >>= 1) l += __shfl_xor(l, off);
        s_probs[t] = e / l;
    }
    __syncthreads();
    {
        const int j = t & 31;
        const int g = t >> 5;
        float4 acc = make_float4(0.f, 0.f, 0.f, 0.f);
#pragma unroll
        for (int i = 0; i < 8; ++i) {
            const int w  = g * 8 + i;
            const float pr = s_probs[w];
            const int   c  = s_cols[w];
            const float4 vv = ((const float4*)(vbase + (size_t)c * Dc))[j];
            acc.x += pr * vv.x;
            acc.y += pr * vv.y;
            acc.z += pr * vv.z;
            acc.w += pr * vv.w;
        }
        ((float4*)s_red)[g * 32 + j] = acc;
    }
    __syncthreads();
    if (t < Dc) {
        float sv = 0.0f;
#pragma unroll
        for (int g = 0; g < 8; ++g) sv += s_red[g * Dc + t];
        out[((size_t)bh * Nc + n) * Dc + t] = sv;
    }
}

extern "C" void kernel_launch(void* const* d_in, const int* in_sizes, int n_in,
                              void* d_out, int out_size, void* d_ws, size_t ws_size,
                              hipStream_t stream) {
    const float* q       = (const float*)d_in[0];
    const float* k       = (const float*)d_in[1];
    const float* v       = (const float*)d_in[2];
    const int*   col_ids = (const int*)  d_in[3];
    float*       out     = (float*)d_out;

    const int n_rows = Bc * Hc * Nc;                 // 49152 rows
    const size_t need = (size_t)2 * ELEMS * sizeof(unsigned short);  // 25.2 MB

    if (ws_size >= need) {
        unsigned short* kbp = (unsigned short*)d_ws;
        unsigned short* vbp = kbp + ELEMS;
        cvt_kernel<<<dim3(ELEMS / 4 / 256), dim3(256), 0, stream>>>(k, v, kbp, vbp);
        sca_wave_kernel<<<dim3(n_rows / 4), dim3(256), 0, stream>>>(q, kbp, vbp, col_ids, out);
    } else {
        sca_kernel<<<dim3(n_rows), dim3(256), 0, stream>>>(q, k, v, col_ids, out);
    }
}

// Round 4
// 202.028 us; speedup vs baseline: 1.2485x; 1.0361x over previous
//
#include <hip/hip_runtime.h>
#include <hip/hip_bf16.h>

// Problem constants (B, H, N, D, W) = (2, 12, 2048, 128, 64)
constexpr int Bc = 2;
constexpr int Hc = 12;
constexpr int Nc = 2048;   // power of two
constexpr int Dc = 128;
constexpr int Wc = 64;
constexpr float SCALE = 0.08838834764831845f;  // 1/sqrt(128)
constexpr int ELEMS = Bc * Hc * Nc * Dc;       // 6,291,456 per tensor

__device__ __forceinline__ float bf_lo(unsigned u) {
    u <<= 16;
    return __builtin_bit_cast(float, u);
}
__device__ __forceinline__ float bf_hi(unsigned u) {
    u &= 0xffff0000u;
    return __builtin_bit_cast(float, u);
}
__device__ __forceinline__ unsigned short f2bf(float f) {
    __hip_bfloat16 h = __float2bfloat16(f);   // RNE
    return __builtin_bit_cast(unsigned short, h);
}

// ---------- fp32 -> bf16 staging for k and v ----------
__global__ __launch_bounds__(256) void cvt_kernel(
    const float* __restrict__ k,
    const float* __restrict__ v,
    unsigned short* __restrict__ kb,
    unsigned short* __restrict__ vb)
{
    const int i = blockIdx.x * 256 + threadIdx.x;   // float4 index
    const float4 kk = ((const float4*)k)[i];
    const float4 vv = ((const float4*)v)[i];
    ushort4 ko, vo;
    ko.x = f2bf(kk.x); ko.y = f2bf(kk.y); ko.z = f2bf(kk.z); ko.w = f2bf(kk.w);
    vo.x = f2bf(vv.x); vo.y = f2bf(vv.y); vo.z = f2bf(vv.z); vo.w = f2bf(vv.w);
    ((ushort4*)kb)[i] = ko;
    ((ushort4*)vb)[i] = vo;
}

// ---------- wave-per-row gather attention, zero block barriers ----------
// Wave (64 lanes) owns one query row. 4 waves per 256-block, independent.
//  QK:  4 column-passes; 4 lanes/column read 64B k-chunks (line-optimal);
//       q row cached in 32 VGPRs; quad shfl-reduce.
//  Softmax: quad-redundant butterfly over xor 4..32.
//  {col,prob} -> per-wave LDS (uint2); DS in-order per wave, no barrier.
//  PV:  4 groups x 16 lanes; one FULL 256B v-row per group per iter
//       (uint4 = 16B/lane); 16 iters; cross-group shfl_xor(16,32);
//       store by lanes 0..15, 32B each (full 512B fp32 row).
__global__ __launch_bounds__(256) void sca_wave_kernel(
    const float* __restrict__ q,
    const unsigned short* __restrict__ kb,
    const unsigned short* __restrict__ vb,
    const int*   __restrict__ col_ids,
    float*       __restrict__ out)
{
    const int t    = threadIdx.x;
    const int wv   = t >> 6;                 // wave 0..3
    const int lane = t & 63;
    const int row  = blockIdx.x * 4 + wv;    // bh*2048 + n
    const int n    = row & (Nc - 1);
    const int bh   = row >> 11;

    __shared__ uint2 s_pc[4][Wc];            // {col, prob} per wave, 2 KiB

    // each lane owns column `lane`
    const int c_own = col_ids[n * Wc + lane];

    const float*          qrow  = q  + (size_t)row * Dc;
    const unsigned short* kbase = kb + (size_t)bh * Nc * Dc;
    const unsigned short* vbase = vb + (size_t)bh * Nc * Dc;

    const int p  = lane & 3;                 // quarter within the quad
    const int qd = lane >> 2;                // quad index 0..15

    // q register cache: lane covers chunks p, p+4, p+8, p+12 (8 dims each)
    float4 qreg[8];
#pragma unroll
    for (int i = 0; i < 4; ++i) {
        qreg[2 * i]     = ((const float4*)qrow)[(p + 4 * i) * 2];
        qreg[2 * i + 1] = ((const float4*)qrow)[(p + 4 * i) * 2 + 1];
    }

    // ---------- QK: 4 passes of 16 columns ----------
    float sc[4];
    int   cs[4];
#pragma unroll
    for (int P = 0; P < 4; ++P) {
        const int w  = P * 16 + qd;
        const int cc = __shfl(c_own, w);
        cs[P] = cc;
        const uint4* krow = (const uint4*)(kbase + (size_t)cc * Dc);
        float acc = 0.0f;
#pragma unroll
        for (int i = 0; i < 4; ++i) {
            const uint4  kk = krow[p + 4 * i];
            const float4 qa = qreg[2 * i];
            const float4 qb = qreg[2 * i + 1];
            acc += bf_lo(kk.x) * qa.x + bf_hi(kk.x) * qa.y
                 + bf_lo(kk.y) * qa.z + bf_hi(kk.y) * qa.w
                 + bf_lo(kk.z) * qb.x + bf_hi(kk.z) * qb.y
                 + bf_lo(kk.w) * qb.z + bf_hi(kk.w) * qb.w;
        }
        acc += __shfl_xor(acc, 1);
        acc += __shfl_xor(acc, 2);
        sc[P] = acc * SCALE;
    }

    // ---------- softmax (quad-redundant over 16 quads) ----------
    float m = fmaxf(fmaxf(sc[0], sc[1]), fmaxf(sc[2], sc[3]));
#pragma unroll
    for (int off = 4; off < 64; off <<= 1) m = fmaxf(m, __shfl_xor(m, off));
    float e0 = __expf(sc[0] - m), e1 = __expf(sc[1] - m);
    float e2 = __expf(sc[2] - m), e3 = __expf(sc[3] - m);
    float s = e0 + e1 + e2 + e3;
#pragma unroll
    for (int off = 4; off < 64; off <<= 1) s += __shfl_xor(s, off);
    const float inv = 1.0f / s;

    // quad leaders publish {col, prob} for their 4 columns
    if (p == 0) {
        s_pc[wv][qd]      = make_uint2((unsigned)cs[0], __float_as_uint(e0 * inv));
        s_pc[wv][16 + qd] = make_uint2((unsigned)cs[1], __float_as_uint(e1 * inv));
        s_pc[wv][32 + qd] = make_uint2((unsigned)cs[2], __float_as_uint(e2 * inv));
        s_pc[wv][48 + qd] = make_uint2((unsigned)cs[3], __float_as_uint(e3 * inv));
    }
    __builtin_amdgcn_wave_barrier();   // ordering only; DS is in-order per wave

    // ---------- PV: 4 groups x 16 lanes, full 256B v-row per group-iter ----------
    const int g = lane >> 4;                 // group 0..3
    const int j = lane & 15;                 // 16B chunk within 256B v-row
    float4 accA = make_float4(0.f, 0.f, 0.f, 0.f);   // dims 8j .. 8j+3
    float4 accB = make_float4(0.f, 0.f, 0.f, 0.f);   // dims 8j+4 .. 8j+7
#pragma unroll
    for (int i = 0; i < 16; ++i) {
        const uint2 pc = s_pc[wv][4 * i + g];        // broadcast (4 addrs/wave)
        const float pr = __uint_as_float(pc.y);
        const uint4 vv = ((const uint4*)(vbase + (size_t)pc.x * Dc))[j]; // 8 bf16
        accA.x += pr * bf_lo(vv.x);
        accA.y += pr * bf_hi(vv.x);
        accA.z += pr * bf_lo(vv.y);
        accA.w += pr * bf_hi(vv.y);
        accB.x += pr * bf_lo(vv.z);
        accB.y += pr * bf_hi(vv.z);
        accB.z += pr * bf_lo(vv.w);
        accB.w += pr * bf_hi(vv.w);
    }
    // combine the four groups (same j on lanes j, 16+j, 32+j, 48+j)
#pragma unroll
    for (int off = 16; off <= 32; off <<= 1) {
        accA.x += __shfl_xor(accA.x, off);
        accA.y += __shfl_xor(accA.y, off);
        accA.z += __shfl_xor(accA.z, off);
        accA.w += __shfl_xor(accA.w, off);
        accB.x += __shfl_xor(accB.x, off);
        accB.y += __shfl_xor(accB.y, off);
        accB.z += __shfl_xor(accB.z, off);
        accB.w += __shfl_xor(accB.w, off);
    }

    if (lane < 16) {
        float4* orow = (float4*)(out + (size_t)row * Dc);
        orow[2 * j]     = accA;
        orow[2 * j + 1] = accB;
    }
}

// ---------- fallback: fp32 kernel (used only if ws too small) ----------
__global__ __launch_bounds__(256) void sca_kernel(
    const float* __restrict__ q,
    const float* __restrict__ k,
    const float* __restrict__ v,
    const int*   __restrict__ col_ids,
    float*       __restrict__ out)
{
    const int bid = blockIdx.x;
    const int n   = bid & (Nc - 1);
    const int bh  = bid >> 11;
    const int t   = threadIdx.x;

    __shared__ int   s_cols[Wc];
    __shared__ float s_scores[Wc];
    __shared__ float s_probs[Wc];
    __shared__ float s_red[8 * Dc];

    if (t < Wc) s_cols[t] = col_ids[n * Wc + t];

    const float* qrow  = q + ((size_t)bh * Nc + n) * Dc;
    const float* kbase = k + (size_t)bh * Nc * Dc;
    const float* vbase = v + (size_t)bh * Nc * Dc;

    __syncthreads();
    {
        const int w = t >> 2;
        const int p = t & 3;
        const int c = s_cols[w];
        const float4* krow = (const float4*)(kbase + (size_t)c * Dc);
        const float4* q4   = (const float4*)qrow;
        float acc = 0.0f;
#pragma unroll
        for (int i = 0; i < 8; ++i) {
            const float4 kk = krow[p + 4 * i];
            const float4 qq = q4[p + 4 * i];
            acc += kk.x * qq.x + kk.y * qq.y + kk.z * qq.z + kk.w * qq.w;
        }
        acc += __shfl_xor(acc, 1);
        acc += __shfl_xor(acc, 2);
        if (p == 0) s_scores[w] = acc * SCALE;
    }
    __syncthreads();
    if (t < 64) {
        const float sv = s_scores[t];
        float m = sv;
#pragma unroll
        for (int off = 32; off > 0; off >>= 1) m = fmaxf(m, __shfl_xor(m, off));
        const float e = __expf(sv - m);
        float l = e;
#pragma unroll
        for (int off = 32; off > 0; off >>= 1) l += __shfl_xor(l, off);
        s_probs[t] = e / l;
    }
    __syncthreads();
    {
        const int j = t & 31;
        const int g = t >> 5;
        float4 acc = make_float4(0.f, 0.f, 0.f, 0.f);
#pragma unroll
        for (int i = 0; i < 8; ++i) {
            const int w  = g * 8 + i;
            const float pr = s_probs[w];
            const int   c  = s_cols[w];
            const float4 vv = ((const float4*)(vbase + (size_t)c * Dc))[j];
            acc.x += pr * vv.x;
            acc.y += pr * vv.y;
            acc.z += pr * vv.z;
            acc.w += pr * vv.w;
        }
        ((float4*)s_red)[g * 32 + j] = acc;
    }
    __syncthreads();
    if (t < Dc) {
        float sv = 0.0f;
#pragma unroll
        for (int g = 0; g < 8; ++g) sv += s_red[g * Dc + t];
        out[((size_t)bh * Nc + n) * Dc + t] = sv;
    }
}

extern "C" void kernel_launch(void* const* d_in, const int* in_sizes, int n_in,
                              void* d_out, int out_size, void* d_ws, size_t ws_size,
                              hipStream_t stream) {
    const float* q       = (const float*)d_in[0];
    const float* k       = (const float*)d_in[1];
    const float* v       = (const float*)d_in[2];
    const int*   col_ids = (const int*)  d_in[3];
    float*       out     = (float*)d_out;

    const int n_rows = Bc * Hc * Nc;                 // 49152 rows
    const size_t need = (size_t)2 * ELEMS * sizeof(unsigned short);  // 25.2 MB

    if (ws_size >= need) {
        unsigned short* kbp = (unsigned short*)d_ws;
        unsigned short* vbp = kbp + ELEMS;
        cvt_kernel<<<dim3(ELEMS / 4 / 256), dim3(256), 0, stream>>>(k, v, kbp, vbp);
        sca_wave_kernel<<<dim3(n_rows / 4), dim3(256), 0, stream>>>(q, kbp, vbp, col_ids, out);
    } else {
        sca_kernel<<<dim3(n_rows), dim3(256), 0, stream>>>(q, k, v, col_ids, out);
    }
}

// Round 5
// 198.866 us; speedup vs baseline: 1.2684x; 1.0159x over previous
//
#include <hip/hip_runtime.h>
#include <hip/hip_bf16.h>

// Problem constants (B, H, N, D, W) = (2, 12, 2048, 128, 64)
constexpr int Bc = 2;
constexpr int Hc = 12;
constexpr int Nc = 2048;   // power of two
constexpr int Dc = 128;
constexpr int Wc = 64;
constexpr float SCALE = 0.08838834764831845f;  // 1/sqrt(128)
constexpr int ELEMS = Bc * Hc * Nc * Dc;       // 6,291,456 per tensor

__device__ __forceinline__ float bf_lo(unsigned u) {
    u <<= 16;
    return __builtin_bit_cast(float, u);
}
__device__ __forceinline__ float bf_hi(unsigned u) {
    u &= 0xffff0000u;
    return __builtin_bit_cast(float, u);
}
__device__ __forceinline__ unsigned short f2bf(float f) {
    __hip_bfloat16 h = __float2bfloat16(f);   // RNE
    return __builtin_bit_cast(unsigned short, h);
}

// ---------- fp32 -> bf16 staging for k and v ----------
__global__ __launch_bounds__(256) void cvt_kernel(
    const float* __restrict__ k,
    const float* __restrict__ v,
    unsigned short* __restrict__ kb,
    unsigned short* __restrict__ vb)
{
    const int i = blockIdx.x * 256 + threadIdx.x;   // float4 index
    const float4 kk = ((const float4*)k)[i];
    const float4 vv = ((const float4*)v)[i];
    ushort4 ko, vo;
    ko.x = f2bf(kk.x); ko.y = f2bf(kk.y); ko.z = f2bf(kk.z); ko.w = f2bf(kk.w);
    vo.x = f2bf(vv.x); vo.y = f2bf(vv.y); vo.z = f2bf(vv.z); vo.w = f2bf(vv.w);
    ((ushort4*)kb)[i] = ko;
    ((ushort4*)vb)[i] = vo;
}

// ---------- wave-per-row gather attention: zero LDS, zero barriers ----------
// Wave (64 lanes) owns one query row; everything stays in-register/in-wave.
//  * v-row gather addresses depend ONLY on col_ids -> prefetch v-rows
//    BEFORE/DURING QK+softmax (vpre half 1 up front, vnext half 2 right
//    after softmax), so v latency overlaps QK math and PV math.
//  * probs delivered to PV lanes by shuffle (quad-redundant softmax):
//    column w=4i+g -> prob e[i>>2]*inv from lane 16*(i&3)+4g.
//  QK:  4 passes; 4 lanes/column, 64B k-chunks (line-optimal), quad reduce.
//  PV:  4 groups x 16 lanes; full 256B v-row per group-iter (16B/lane);
//       cross-group shfl_xor(16,32); lanes 0..15 store 32B each.
__global__ __launch_bounds__(256) void sca_wave_kernel(
    const float* __restrict__ q,
    const unsigned short* __restrict__ kb,
    const unsigned short* __restrict__ vb,
    const int*   __restrict__ col_ids,
    float*       __restrict__ out)
{
    const int t    = threadIdx.x;
    const int wv   = t >> 6;                 // wave 0..3 (independent)
    const int lane = t & 63;
    const int row  = blockIdx.x * 4 + wv;    // bh*2048 + n
    const int n    = row & (Nc - 1);
    const int bh   = row >> 11;

    const int c_own = col_ids[n * Wc + lane];   // lane owns column `lane`

    const float*          qrow  = q  + (size_t)row * Dc;
    const unsigned short* kbase = kb + (size_t)bh * Nc * Dc;
    const unsigned short* vbase = vb + (size_t)bh * Nc * Dc;

    const int p  = lane & 3;                 // quarter within the quad
    const int qd = lane >> 2;                // quad index 0..15
    const int g  = lane >> 4;                // PV group 0..3
    const int j  = lane & 15;                // 16B chunk within 256B v-row

    // ---- PV prefetch half 1: independent of scores, issue FIRST ----
    uint4 vpre[8];
#pragma unroll
    for (int i = 0; i < 8; ++i) {
        const int cc = __shfl(c_own, 4 * i + g);
        vpre[i] = ((const uint4*)(vbase + (size_t)cc * Dc))[j];
    }

    // ---- q register cache: lane covers chunks p, p+4, p+8, p+12 ----
    float4 qreg[8];
#pragma unroll
    for (int i = 0; i < 4; ++i) {
        qreg[2 * i]     = ((const float4*)qrow)[(p + 4 * i) * 2];
        qreg[2 * i + 1] = ((const float4*)qrow)[(p + 4 * i) * 2 + 1];
    }

    // ---------- QK: 4 passes of 16 columns ----------
    float sc[4];
#pragma unroll
    for (int P = 0; P < 4; ++P) {
        const int cc = __shfl(c_own, P * 16 + qd);
        const uint4* krow = (const uint4*)(kbase + (size_t)cc * Dc);
        float acc = 0.0f;
#pragma unroll
        for (int i = 0; i < 4; ++i) {
            const uint4  kk = krow[p + 4 * i];
            const float4 qa = qreg[2 * i];
            const float4 qb = qreg[2 * i + 1];
            acc += bf_lo(kk.x) * qa.x + bf_hi(kk.x) * qa.y
                 + bf_lo(kk.y) * qa.z + bf_hi(kk.y) * qa.w
                 + bf_lo(kk.z) * qb.x + bf_hi(kk.z) * qb.y
                 + bf_lo(kk.w) * qb.z + bf_hi(kk.w) * qb.w;
        }
        acc += __shfl_xor(acc, 1);
        acc += __shfl_xor(acc, 2);
        sc[P] = acc * SCALE;
    }

    // ---------- softmax (quad-redundant over 16 quads) ----------
    float m = fmaxf(fmaxf(sc[0], sc[1]), fmaxf(sc[2], sc[3]));
#pragma unroll
    for (int off = 4; off < 64; off <<= 1) m = fmaxf(m, __shfl_xor(m, off));
    const float e0 = __expf(sc[0] - m), e1 = __expf(sc[1] - m);
    const float e2 = __expf(sc[2] - m), e3 = __expf(sc[3] - m);
    float s = e0 + e1 + e2 + e3;
#pragma unroll
    for (int off = 4; off < 64; off <<= 1) s += __shfl_xor(s, off);
    const float inv = 1.0f / s;
    float pn[4] = { e0 * inv, e1 * inv, e2 * inv, e3 * inv };

    // ---- PV prefetch half 2: issue before consuming half 1 ----
    uint4 vnext[8];
#pragma unroll
    for (int i = 0; i < 8; ++i) {
        const int cc = __shfl(c_own, 4 * (i + 8) + g);
        vnext[i] = ((const uint4*)(vbase + (size_t)cc * Dc))[j];
    }

    // ---------- PV accumulate: column w = 4i+g ----------
    float4 accA = make_float4(0.f, 0.f, 0.f, 0.f);   // dims 8j .. 8j+3
    float4 accB = make_float4(0.f, 0.f, 0.f, 0.f);   // dims 8j+4 .. 8j+7
#pragma unroll
    for (int i = 0; i < 16; ++i) {
        const uint4 vv = (i < 8) ? vpre[i & 7] : vnext[i & 7];
        // prob for column 4i+g: element i>>2 from lane 16*(i&3)+4g
        const float pr = __shfl(pn[i >> 2], 16 * (i & 3) + 4 * g);
        accA.x += pr * bf_lo(vv.x);
        accA.y += pr * bf_hi(vv.x);
        accA.z += pr * bf_lo(vv.y);
        accA.w += pr * bf_hi(vv.y);
        accB.x += pr * bf_lo(vv.z);
        accB.y += pr * bf_hi(vv.z);
        accB.z += pr * bf_lo(vv.w);
        accB.w += pr * bf_hi(vv.w);
    }
    // combine the four groups (same j on lanes j, 16+j, 32+j, 48+j)
#pragma unroll
    for (int off = 16; off <= 32; off <<= 1) {
        accA.x += __shfl_xor(accA.x, off);
        accA.y += __shfl_xor(accA.y, off);
        accA.z += __shfl_xor(accA.z, off);
        accA.w += __shfl_xor(accA.w, off);
        accB.x += __shfl_xor(accB.x, off);
        accB.y += __shfl_xor(accB.y, off);
        accB.z += __shfl_xor(accB.z, off);
        accB.w += __shfl_xor(accB.w, off);
    }

    if (lane < 16) {
        float4* orow = (float4*)(out + (size_t)row * Dc);
        orow[2 * j]     = accA;
        orow[2 * j + 1] = accB;
    }
}

// ---------- fallback: fp32 kernel (used only if ws too small) ----------
__global__ __launch_bounds__(256) void sca_kernel(
    const float* __restrict__ q,
    const float* __restrict__ k,
    const float* __restrict__ v,
    const int*   __restrict__ col_ids,
    float*       __restrict__ out)
{
    const int bid = blockIdx.x;
    const int n   = bid & (Nc - 1);
    const int bh  = bid >> 11;
    const int t   = threadIdx.x;

    __shared__ int   s_cols[Wc];
    __shared__ float s_scores[Wc];
    __shared__ float s_probs[Wc];
    __shared__ float s_red[8 * Dc];

    if (t < Wc) s_cols[t] = col_ids[n * Wc + t];

    const float* qrow  = q + ((size_t)bh * Nc + n) * Dc;
    const float* kbase = k + (size_t)bh * Nc * Dc;
    const float* vbase = v + (size_t)bh * Nc * Dc;

    __syncthreads();
    {
        const int w = t >> 2;
        const int p = t & 3;
        const int c = s_cols[w];
        const float4* krow = (const float4*)(kbase + (size_t)c * Dc);
        const float4* q4   = (const float4*)qrow;
        float acc = 0.0f;
#pragma unroll
        for (int i = 0; i < 8; ++i) {
            const float4 kk = krow[p + 4 * i];
            const float4 qq = q4[p + 4 * i];
            acc += kk.x * qq.x + kk.y * qq.y + kk.z * qq.z + kk.w * qq.w;
        }
        acc += __shfl_xor(acc, 1);
        acc += __shfl_xor(acc, 2);
        if (p == 0) s_scores[w] = acc * SCALE;
    }
    __syncthreads();
    if (t < 64) {
        const float sv = s_scores[t];
        float m = sv;
#pragma unroll
        for (int off = 32; off > 0; off >>= 1) m = fmaxf(m, __shfl_xor(m, off));
        const float e = __expf(sv - m);
        float l = e;
#pragma unroll
        for (int off = 32; off > 0; off >>= 1) l += __shfl_xor(l, off);
        s_probs[t] = e / l;
    }
    __syncthreads();
    {
        const int j = t & 31;
        const int g = t >> 5;
        float4 acc = make_float4(0.f, 0.f, 0.f, 0.f);
#pragma unroll
        for (int i = 0; i < 8; ++i) {
            const int w  = g * 8 + i;
            const float pr = s_probs[w];
            const int   c  = s_cols[w];
            const float4 vv = ((const float4*)(vbase + (size_t)c * Dc))[j];
            acc.x += pr * vv.x;
            acc.y += pr * vv.y;
            acc.z += pr * vv.z;
            acc.w += pr * vv.w;
        }
        ((float4*)s_red)[g * 32 + j] = acc;
    }
    __syncthreads();
    if (t < Dc) {
        float sv = 0.0f;
#pragma unroll
        for (int g = 0; g < 8; ++g) sv += s_red[g * Dc + t];
        out[((size_t)bh * Nc + n) * Dc + t] = sv;
    }
}

extern "C" void kernel_launch(void* const* d_in, const int* in_sizes, int n_in,
                              void* d_out, int out_size, void* d_ws, size_t ws_size,
                              hipStream_t stream) {
    const float* q       = (const float*)d_in[0];
    const float* k       = (const float*)d_in[1];
    const float* v       = (const float*)d_in[2];
    const int*   col_ids = (const int*)  d_in[3];
    float*       out     = (float*)d_out;

    const int n_rows = Bc * Hc * Nc;                 // 49152 rows
    const size_t need = (size_t)2 * ELEMS * sizeof(unsigned short);  // 25.2 MB

    if (ws_size >= need) {
        unsigned short* kbp = (unsigned short*)d_ws;
        unsigned short* vbp = kbp + ELEMS;
        cvt_kernel<<<dim3(ELEMS / 4 / 256), dim3(256), 0, stream>>>(k, v, kbp, vbp);
        sca_wave_kernel<<<dim3(n_rows / 4), dim3(256), 0, stream>>>(q, kbp, vbp, col_ids, out);
    } else {
        sca_kernel<<<dim3(n_rows), dim3(256), 0, stream>>>(q, k, v, col_ids, out);
    }
}

// Round 6
// 186.632 us; speedup vs baseline: 1.3515x; 1.0656x over previous
//
#include <hip/hip_runtime.h>
#include <hip/hip_bf16.h>

// Problem constants (B, H, N, D, W) = (2, 12, 2048, 128, 64)
constexpr int Bc = 2;
constexpr int Hc = 12;
constexpr int Nc = 2048;   // power of two
constexpr int Dc = 128;
constexpr int Wc = 64;
constexpr float SCALE = 0.08838834764831845f;  // 1/sqrt(128)
constexpr int ELEMS = Bc * Hc * Nc * Dc;       // 6,291,456 per tensor

__device__ __forceinline__ float bf_lo(unsigned u) {
    u <<= 16;
    return __builtin_bit_cast(float, u);
}
__device__ __forceinline__ float bf_hi(unsigned u) {
    u &= 0xffff0000u;
    return __builtin_bit_cast(float, u);
}
__device__ __forceinline__ unsigned short f2bf(float f) {
    __hip_bfloat16 h = __float2bfloat16(f);   // RNE
    return __builtin_bit_cast(unsigned short, h);
}

// ---------- fp32 -> bf16 staging for k and v ----------
__global__ __launch_bounds__(256) void cvt_kernel(
    const float* __restrict__ k,
    const float* __restrict__ v,
    unsigned short* __restrict__ kb,
    unsigned short* __restrict__ vb)
{
    const int i = blockIdx.x * 256 + threadIdx.x;   // float4 index
    const float4 kk = ((const float4*)k)[i];
    const float4 vv = ((const float4*)v)[i];
    ushort4 ko, vo;
    ko.x = f2bf(kk.x); ko.y = f2bf(kk.y); ko.z = f2bf(kk.z); ko.w = f2bf(kk.w);
    vo.x = f2bf(vv.x); vo.y = f2bf(vv.y); vo.z = f2bf(vv.z); vo.w = f2bf(vv.w);
    ((ushort4*)kb)[i] = ko;
    ((ushort4*)vb)[i] = vo;
}

// ---------- wave-per-row gather attention: zero LDS, 128B-granular loads ----
// Wave (64 lanes) owns one query row.
//  QK:  8 passes of 8 columns; 8 lanes (octet) per column, each lane 16B ->
//       every k-row request is 128B-contiguous (2 per 256B row).
//       Octet reduce via shfl_xor 1,2,4.
//  Softmax: octet-redundant butterfly over xor 8,16,32 (8 scores per lane).
//  PV:  4 groups x 16 lanes; full 256B v-row per group-iter (16B/lane, two
//       128B requests); prob for col w=4i+g shuffled from lane 32*(i&1)+8g,
//       element i>>1. Cross-group shfl_xor(16,32); lanes 0..15 store 32B.
__global__ __launch_bounds__(256) void sca_wave_kernel(
    const float* __restrict__ q,
    const unsigned short* __restrict__ kb,
    const unsigned short* __restrict__ vb,
    const int*   __restrict__ col_ids,
    float*       __restrict__ out)
{
    const int t    = threadIdx.x;
    const int wv   = t >> 6;                 // wave 0..3 (independent)
    const int lane = t & 63;
    const int row  = blockIdx.x * 4 + wv;    // bh*2048 + n
    const int n    = row & (Nc - 1);
    const int bh   = row >> 11;

    const int c_own = col_ids[n * Wc + lane];   // lane owns column `lane`

    const float*          qrow  = q  + (size_t)row * Dc;
    const unsigned short* kbase = kb + (size_t)bh * Nc * Dc;
    const unsigned short* vbase = vb + (size_t)bh * Nc * Dc;

    const int p8 = lane & 7;                 // position within octet
    const int o8 = lane >> 3;                // octet 0..7
    const int g  = lane >> 4;                // PV group 0..3
    const int j  = lane & 15;                // 16B chunk within 256B v-row

    // q cache: dims 8*p8..8*p8+7 (first row half) and 64+8*p8.. (second half)
    const float4* q4 = (const float4*)qrow;
    const float4 qa0 = q4[2 * p8];
    const float4 qa1 = q4[2 * p8 + 1];
    const float4 qb0 = q4[16 + 2 * p8];
    const float4 qb1 = q4[16 + 2 * p8 + 1];

    // ---------- QK: 8 passes of 8 columns, 128B-granular ----------
    float sc[8];
#pragma unroll
    for (int P = 0; P < 8; ++P) {
        const int cc = __shfl(c_own, 8 * P + o8);
        const uint4* krow = (const uint4*)(kbase + (size_t)cc * Dc);
        const uint4 k0 = krow[p8];           // octet covers bytes 0..127
        const uint4 k1 = krow[8 + p8];       // octet covers bytes 128..255
        float acc =
              bf_lo(k0.x) * qa0.x + bf_hi(k0.x) * qa0.y
            + bf_lo(k0.y) * qa0.z + bf_hi(k0.y) * qa0.w
            + bf_lo(k0.z) * qa1.x + bf_hi(k0.z) * qa1.y
            + bf_lo(k0.w) * qa1.z + bf_hi(k0.w) * qa1.w
            + bf_lo(k1.x) * qb0.x + bf_hi(k1.x) * qb0.y
            + bf_lo(k1.y) * qb0.z + bf_hi(k1.y) * qb0.w
            + bf_lo(k1.z) * qb1.x + bf_hi(k1.z) * qb1.y
            + bf_lo(k1.w) * qb1.z + bf_hi(k1.w) * qb1.w;
        acc += __shfl_xor(acc, 1);
        acc += __shfl_xor(acc, 2);
        acc += __shfl_xor(acc, 4);
        sc[P] = acc * SCALE;                 // col 8P + o8, octet-redundant
    }

    // ---------- softmax (octet-redundant butterfly) ----------
    float m = sc[0];
#pragma unroll
    for (int P = 1; P < 8; ++P) m = fmaxf(m, sc[P]);
#pragma unroll
    for (int off = 8; off < 64; off <<= 1) m = fmaxf(m, __shfl_xor(m, off));
    float e[8];
    float s = 0.0f;
#pragma unroll
    for (int P = 0; P < 8; ++P) { e[P] = __expf(sc[P] - m); s += e[P]; }
#pragma unroll
    for (int off = 8; off < 64; off <<= 1) s += __shfl_xor(s, off);
    const float inv = 1.0f / s;
    float pn[8];
#pragma unroll
    for (int P = 0; P < 8; ++P) pn[P] = e[P] * inv;

    // ---------- PV: 4 groups x 16 lanes, full 256B v-row per group-iter ----
    float4 accA = make_float4(0.f, 0.f, 0.f, 0.f);   // dims 8j .. 8j+3
    float4 accB = make_float4(0.f, 0.f, 0.f, 0.f);   // dims 8j+4 .. 8j+7
#pragma unroll
    for (int i = 0; i < 16; ++i) {
        const int cc = __shfl(c_own, 4 * i + g);     // col w = 4i+g
        // owner octet of col w is w&7 = 4*(i&1)+g; element index = w>>3 = i>>1
        const float pr = __shfl(pn[i >> 1], 32 * (i & 1) + 8 * g);
        const uint4 vv = ((const uint4*)(vbase + (size_t)cc * Dc))[j];
        accA.x += pr * bf_lo(vv.x);
        accA.y += pr * bf_hi(vv.x);
        accA.z += pr * bf_lo(vv.y);
        accA.w += pr * bf_hi(vv.y);
        accB.x += pr * bf_lo(vv.z);
        accB.y += pr * bf_hi(vv.z);
        accB.z += pr * bf_lo(vv.w);
        accB.w += pr * bf_hi(vv.w);
    }
    // combine the four groups (same j on lanes j, 16+j, 32+j, 48+j)
#pragma unroll
    for (int off = 16; off <= 32; off <<= 1) {
        accA.x += __shfl_xor(accA.x, off);
        accA.y += __shfl_xor(accA.y, off);
        accA.z += __shfl_xor(accA.z, off);
        accA.w += __shfl_xor(accA.w, off);
        accB.x += __shfl_xor(accB.x, off);
        accB.y += __shfl_xor(accB.y, off);
        accB.z += __shfl_xor(accB.z, off);
        accB.w += __shfl_xor(accB.w, off);
    }

    if (lane < 16) {
        float4* orow = (float4*)(out + (size_t)row * Dc);
        orow[2 * j]     = accA;
        orow[2 * j + 1] = accB;
    }
}

// ---------- fallback: fp32 kernel (used only if ws too small) ----------
__global__ __launch_bounds__(256) void sca_kernel(
    const float* __restrict__ q,
    const float* __restrict__ k,
    const float* __restrict__ v,
    const int*   __restrict__ col_ids,
    float*       __restrict__ out)
{
    const int bid = blockIdx.x;
    const int n   = bid & (Nc - 1);
    const int bh  = bid >> 11;
    const int t   = threadIdx.x;

    __shared__ int   s_cols[Wc];
    __shared__ float s_scores[Wc];
    __shared__ float s_probs[Wc];
    __shared__ float s_red[8 * Dc];

    if (t < Wc) s_cols[t] = col_ids[n * Wc + t];

    const float* qrow  = q + ((size_t)bh * Nc + n) * Dc;
    const float* kbase = k + (size_t)bh * Nc * Dc;
    const float* vbase = v + (size_t)bh * Nc * Dc;

    __syncthreads();
    {
        const int w = t >> 2;
        const int p = t & 3;
        const int c = s_cols[w];
        const float4* krow = (const float4*)(kbase + (size_t)c * Dc);
        const float4* q4   = (const float4*)qrow;
        float acc = 0.0f;
#pragma unroll
        for (int i = 0; i < 8; ++i) {
            const float4 kk = krow[p + 4 * i];
            const float4 qq = q4[p + 4 * i];
            acc += kk.x * qq.x + kk.y * qq.y + kk.z * qq.z + kk.w * qq.w;
        }
        acc += __shfl_xor(acc, 1);
        acc += __shfl_xor(acc, 2);
        if (p == 0) s_scores[w] = acc * SCALE;
    }
    __syncthreads();
    if (t < 64) {
        const float sv = s_scores[t];
        float m = sv;
#pragma unroll
        for (int off = 32; off > 0; off >>= 1) m = fmaxf(m, __shfl_xor(m, off));
        const float e = __expf(sv - m);
        float l = e;
#pragma unroll
        for (int off = 32; off > 0; off >>= 1) l += __shfl_xor(l, off);
        s_probs[t] = e / l;
    }
    __syncthreads();
    {
        const int j = t & 31;
        const int g = t >> 5;
        float4 acc = make_float4(0.f, 0.f, 0.f, 0.f);
#pragma unroll
        for (int i = 0; i < 8; ++i) {
            const int w  = g * 8 + i;
            const float pr = s_probs[w];
            const int   c  = s_cols[w];
            const float4 vv = ((const float4*)(vbase + (size_t)c * Dc))[j];
            acc.x += pr * vv.x;
            acc.y += pr * vv.y;
            acc.z += pr * vv.z;
            acc.w += pr * vv.w;
        }
        ((float4*)s_red)[g * 32 + j] = acc;
    }
    __syncthreads();
    if (t < Dc) {
        float sv = 0.0f;
#pragma unroll
        for (int g = 0; g < 8; ++g) sv += s_red[g * Dc + t];
        out[((size_t)bh * Nc + n) * Dc + t] = sv;
    }
}

extern "C" void kernel_launch(void* const* d_in, const int* in_sizes, int n_in,
                              void* d_out, int out_size, void* d_ws, size_t ws_size,
                              hipStream_t stream) {
    const float* q       = (const float*)d_in[0];
    const float* k       = (const float*)d_in[1];
    const float* v       = (const float*)d_in[2];
    const int*   col_ids = (const int*)  d_in[3];
    float*       out     = (float*)d_out;

    const int n_rows = Bc * Hc * Nc;                 // 49152 rows
    const size_t need = (size_t)2 * ELEMS * sizeof(unsigned short);  // 25.2 MB

    if (ws_size >= need) {
        unsigned short* kbp = (unsigned short*)d_ws;
        unsigned short* vbp = kbp + ELEMS;
        cvt_kernel<<<dim3(ELEMS / 4 / 256), dim3(256), 0, stream>>>(k, v, kbp, vbp);
        sca_wave_kernel<<<dim3(n_rows / 4), dim3(256), 0, stream>>>(q, kbp, vbp, col_ids, out);
    } else {
        sca_kernel<<<dim3(n_rows), dim3(256), 0, stream>>>(q, k, v, col_ids, out);
    }
}